// Round 1
// baseline (902.902 us; speedup 1.0000x reference)
//
#include <hip/hip_runtime.h>
#include <math.h>

// ---------------------------------------------------------------------------
// TACE (MACE-style equivariant GNN) forward on MI355X.
// N=5000 nodes, E=80000 edges, C=64, 2 layers, ranks 0..3 (dims 1,3,9,27).
//
// Pipeline per launch:
//   1. k_edge_basis: rb[E,8] (Bessel-j0 * poly cutoff), Y[E,40] angular.
//   2. CSR build by receiver (hist + scan + scatter + per-node sort).
//   3. k_embed: h0[N,64] = embed_w[species].
//   4. per layer: k_edge_mlp (radial MLP -> t[E,4,64] = R * h0[senders]),
//                 k_node (gather-segment-sum -> A, contract, mix, readout).
// ---------------------------------------------------------------------------

#define PI_F 3.14159265358979323846f

__device__ __forceinline__ float silu_f(float x) {
    return x / (1.0f + expf(-x));
}

// ---------------- edge basis + angular ----------------
__global__ void k_edge_basis(const float* __restrict__ ev,
                             float* __restrict__ rb,
                             float* __restrict__ Yb, int E)
{
    int e = blockIdx.x * blockDim.x + threadIdx.x;
    if (e >= E) return;
    float vx = ev[3*e+0], vy = ev[3*e+1], vz = ev[3*e+2];
    float r2 = vx*vx + vy*vy + vz*vz + 1e-12f;
    float r  = sqrtf(r2);
    float x  = r * 0.2f;                   // r / CUTOFF
    float x2 = x*x;
    float x5 = x2*x2*x;
    // env = 1 - 21 x^5 + 35 x^6 - 15 x^7   (P=5)
    float env = 1.0f + x5*(-21.0f + x*(35.0f - 15.0f*x));
    if (x >= 1.0f) env = 0.0f;
    float pref = 0.632455532033675866f / r * env;   // sqrt(2/5)/r * env
    float pix  = PI_F * x;
    float* rbp = rb + (size_t)e*8;
    #pragma unroll
    for (int k = 0; k < 8; ++k) rbp[k] = pref * sinf((float)(k+1) * pix);

    float ir = 1.0f / r;
    float hv[3];
    hv[0] = vx*ir; hv[1] = vy*ir; hv[2] = vz*ir;
    float* Yr = Yb + (size_t)e*40;
    const float s3 = 1.73205080756887729f;
    const float s5 = 2.23606797749978969f;
    const float s7 = 2.64575131106459059f;
    Yr[0] = 1.0f;
    #pragma unroll
    for (int i = 0; i < 3; ++i) Yr[1+i] = s3*hv[i];
    #pragma unroll
    for (int i = 0; i < 3; ++i)
        #pragma unroll
        for (int j = 0; j < 3; ++j) Yr[4+i*3+j] = s5*hv[i]*hv[j];
    #pragma unroll
    for (int i = 0; i < 3; ++i)
        #pragma unroll
        for (int j = 0; j < 3; ++j)
            #pragma unroll
            for (int k = 0; k < 3; ++k) Yr[13+i*9+j*3+k] = s7*hv[i]*hv[j]*hv[k];
}

// ---------------- CSR build ----------------
__global__ void k_hist(const int* __restrict__ recv, int* __restrict__ counts, int E)
{
    int e = blockIdx.x * blockDim.x + threadIdx.x;
    if (e < E) atomicAdd(&counts[recv[e]], 1);
}

__global__ void k_scan(const int* __restrict__ counts, int* __restrict__ offsets, int N)
{
    __shared__ int lds[1024];
    __shared__ int basev;
    if (threadIdx.x == 0) basev = 0;
    __syncthreads();
    for (int start = 0; start < N; start += 1024) {
        int i = start + (int)threadIdx.x;
        int v = (i < N) ? counts[i] : 0;
        lds[threadIdx.x] = v;
        __syncthreads();
        for (int off = 1; off < 1024; off <<= 1) {
            int add = (threadIdx.x >= (unsigned)off) ? lds[threadIdx.x - off] : 0;
            __syncthreads();
            lds[threadIdx.x] += add;
            __syncthreads();
        }
        if (i < N) offsets[i] = basev + lds[threadIdx.x] - v;  // exclusive
        __syncthreads();
        if (threadIdx.x == 1023) basev += lds[1023];
        __syncthreads();
    }
    if (threadIdx.x == 0) offsets[N] = basev;
}

__global__ void k_scatter(const int* __restrict__ recv,
                          const int* __restrict__ offsets,
                          int* __restrict__ cursor,
                          int* __restrict__ elist, int E)
{
    int e = blockIdx.x * blockDim.x + threadIdx.x;
    if (e >= E) return;
    int r = recv[e];
    int p = atomicAdd(&cursor[r], 1);
    elist[offsets[r] + p] = e;
}

__global__ void k_sort(const int* __restrict__ offsets, int* __restrict__ elist, int N)
{
    int n = blockIdx.x * blockDim.x + threadIdx.x;
    if (n >= N) return;
    int b = offsets[n], e2 = offsets[n+1];
    for (int i = b + 1; i < e2; ++i) {
        int v = elist[i];
        int j = i - 1;
        while (j >= b && elist[j] > v) { elist[j+1] = elist[j]; --j; }
        elist[j+1] = v;
    }
}

__global__ void k_embed(const int* __restrict__ species,
                        const float* __restrict__ embw,
                        float* __restrict__ h0, int NC)
{
    int i = blockIdx.x * blockDim.x + threadIdx.x;
    if (i >= NC) return;
    int n = i >> 6, c = i & 63;
    h0[i] = embw[species[n]*64 + c];
}

// ---------------- edge radial MLP + sender gather ----------------
// One wave (64 lanes) per 64 edges; lane = its own edge. Hidden state in
// registers; weights are wave-uniform (scalar-operand FMAs).
__global__ __launch_bounds__(64) void k_edge_mlp(
    const float* __restrict__ rb,       // [E,8]
    const float* __restrict__ h0,       // [N,64]
    const int*   __restrict__ senders,  // [E]
    const float* __restrict__ w1,       // [8,64]
    const float* __restrict__ w2,       // [64,64]
    const float* __restrict__ w3,       // [64,64]
    const float* __restrict__ w4,       // [64,256]
    float* __restrict__ tout,           // [E,256]
    int E)
{
    __shared__ float xch[64][65];
    int lane = threadIdx.x;
    int base = blockIdx.x * 64;
    int e = base + lane;
    bool val = (e < E);

    float rbv[8];
    if (val) {
        #pragma unroll
        for (int k = 0; k < 8; ++k) rbv[k] = rb[(size_t)e*8 + k];
    } else {
        #pragma unroll
        for (int k = 0; k < 8; ++k) rbv[k] = 0.0f;
    }

    float ha[64], hb[64];
    // stage 1: ha = silu(rb @ w1)
    #pragma unroll
    for (int c = 0; c < 64; ++c) ha[c] = 0.0f;
    #pragma unroll
    for (int k = 0; k < 8; ++k) {
        float v = rbv[k];
        #pragma unroll
        for (int c = 0; c < 64; ++c) ha[c] = fmaf(v, w1[k*64 + c], ha[c]);
    }
    #pragma unroll
    for (int c = 0; c < 64; ++c) ha[c] = silu_f(ha[c]);

    // stage 2: hb = silu(ha @ w2)
    #pragma unroll
    for (int c = 0; c < 64; ++c) hb[c] = 0.0f;
    #pragma unroll
    for (int j = 0; j < 64; ++j) {
        float v = ha[j];
        #pragma unroll
        for (int c = 0; c < 64; ++c) hb[c] = fmaf(v, w2[j*64 + c], hb[c]);
    }
    #pragma unroll
    for (int c = 0; c < 64; ++c) hb[c] = silu_f(hb[c]);

    // stage 3: ha = silu(hb @ w3)
    #pragma unroll
    for (int c = 0; c < 64; ++c) ha[c] = 0.0f;
    #pragma unroll
    for (int j = 0; j < 64; ++j) {
        float v = hb[j];
        #pragma unroll
        for (int c = 0; c < 64; ++c) ha[c] = fmaf(v, w3[j*64 + c], ha[c]);
    }
    #pragma unroll
    for (int c = 0; c < 64; ++c) ha[c] = silu_f(ha[c]);

    // stage 4: R = ha @ w4 per rank chunk; t = R * h0[sender]; coalesced store
    for (int ri = 0; ri < 4; ++ri) {
        float acc[64];
        #pragma unroll
        for (int c = 0; c < 64; ++c) acc[c] = 0.0f;
        #pragma unroll
        for (int j = 0; j < 64; ++j) {
            float v = ha[j];
            #pragma unroll
            for (int c = 0; c < 64; ++c)
                acc[c] = fmaf(v, w4[j*256 + ri*64 + c], acc[c]);
        }
        // transpose via LDS: xch[edge_in_tile][c]
        #pragma unroll
        for (int c = 0; c < 64; ++c) xch[lane][c] = acc[c];
        __syncthreads();
        for (int et = 0; et < 64; ++et) {
            int e2 = base + et;
            if (e2 >= E) break;
            float vv  = xch[et][lane];
            int   snd = senders[e2];
            float hj  = h0[(size_t)snd*64 + lane];
            tout[(size_t)e2*256 + ri*64 + lane] = vv * hj;
        }
        __syncthreads();
    }
}

// ---------------- node gather + contraction + mix + readout ----------------
__global__ __launch_bounds__(256) void k_node(
    const float* __restrict__ tbuf,    // [E,256]
    const float* __restrict__ Yb,      // [E,40]
    const int*   __restrict__ offsets, // [N+1]
    const int*   __restrict__ elist,   // [E]
    const float* __restrict__ mixw,    // [4,64,64] (this layer)
    const float* __restrict__ readw,   // [64]      (this layer)
    float* __restrict__ h0n,           // [N,64]
    const float* __restrict__ eprev,   // [N] or null
    float* __restrict__ eout,          // [N]
    int N)
{
    int gtid = blockIdx.x * blockDim.x + threadIdx.x;
    int wave = gtid >> 6;
    int lane = threadIdx.x & 63;
    int w    = threadIdx.x >> 6;
    __shared__ float Bl[4][4][64];
    bool active = (wave < N);
    int n = active ? wave : 0;

    float A[40];
    #pragma unroll
    for (int d = 0; d < 40; ++d) A[d] = 0.0f;

    if (active) {
        int beg = offsets[n], end = offsets[n+1];
        for (int i = beg; i < end; ++i) {
            int e = elist[i];
            const float* Yr = Yb + (size_t)e*40;
            const float* tr = tbuf + (size_t)e*256;
            float t0 = tr[lane];
            float t1 = tr[64 + lane];
            float t2 = tr[128 + lane];
            float t3 = tr[192 + lane];
            A[0] = fmaf(t0, Yr[0], A[0]);
            #pragma unroll
            for (int d = 0; d < 3; ++d)  A[1+d]  = fmaf(t1, Yr[1+d],  A[1+d]);
            #pragma unroll
            for (int d = 0; d < 9; ++d)  A[4+d]  = fmaf(t2, Yr[4+d],  A[4+d]);
            #pragma unroll
            for (int d = 0; d < 27; ++d) A[13+d] = fmaf(t3, Yr[13+d], A[13+d]);
        }
    }
    const float inv = 1.0f / 16.0f;  // AVG_NEIGH
    #pragma unroll
    for (int d = 0; d < 40; ++d) A[d] *= inv;

    float B0 = A[0];
    float B1 = 0.f, B2 = 0.f, B3 = 0.f;
    #pragma unroll
    for (int d = 0; d < 3; ++d)  B1 = fmaf(A[1+d],  A[1+d],  B1);
    #pragma unroll
    for (int d = 0; d < 9; ++d)  B2 = fmaf(A[4+d],  A[4+d],  B2);
    #pragma unroll
    for (int d = 0; d < 27; ++d) B3 = fmaf(A[13+d], A[13+d], B3);

    Bl[w][0][lane] = B0;
    Bl[w][1][lane] = B1;
    Bl[w][2][lane] = B2;
    Bl[w][3][lane] = B3;
    __syncthreads();

    if (active) {
        float acc = 0.0f;
        for (int ri = 0; ri < 4; ++ri) {
            #pragma unroll 8
            for (int j = 0; j < 64; ++j)
                acc = fmaf(Bl[w][ri][j], mixw[(ri*64 + j)*64 + lane], acc);
        }
        h0n[(size_t)n*64 + lane] = acc;

        float evl = acc * readw[lane];
        #pragma unroll
        for (int off = 1; off < 64; off <<= 1) evl += __shfl_xor(evl, off, 64);
        if (lane == 0) {
            float o = evl;
            if (eprev) o += eprev[n];
            eout[n] = o;
        }
    }
}

// ---------------------------------------------------------------------------
extern "C" void kernel_launch(void* const* d_in, const int* in_sizes, int n_in,
                              void* d_out, int out_size, void* d_ws, size_t ws_size,
                              hipStream_t stream)
{
    const int*   species   = (const int*)  d_in[0];
    const int*   senders   = (const int*)  d_in[1];
    const int*   receivers = (const int*)  d_in[2];
    const float* edge_vec  = (const float*)d_in[3];
    const float* embed_w   = (const float*)d_in[4];
    const float* rad_w1    = (const float*)d_in[5];
    const float* rad_w2    = (const float*)d_in[6];
    const float* rad_w3    = (const float*)d_in[7];
    const float* rad_w4    = (const float*)d_in[8];
    const float* mix_w     = (const float*)d_in[9];
    const float* read_w    = (const float*)d_in[10];

    int N = in_sizes[0];
    int E = in_sizes[1];
    float* out = (float*)d_out;

    char* ws = (char*)d_ws;
    float* rb    = (float*)ws;  ws += (size_t)E*8*sizeof(float);
    float* Yb    = (float*)ws;  ws += (size_t)E*40*sizeof(float);
    float* tbuf  = (float*)ws;  ws += (size_t)E*256*sizeof(float);
    float* h0a   = (float*)ws;  ws += (size_t)N*64*sizeof(float);
    float* h0b   = (float*)ws;  ws += (size_t)N*64*sizeof(float);
    float* ener  = (float*)ws;  ws += (size_t)N*sizeof(float);
    int* counts  = (int*)ws;    ws += (size_t)N*sizeof(int);
    int* offsets = (int*)ws;    ws += (size_t)(N+1)*sizeof(int);
    int* cursor  = (int*)ws;    ws += (size_t)N*sizeof(int);
    int* elist   = (int*)ws;    ws += (size_t)E*sizeof(int);

    hipMemsetAsync(counts, 0, (size_t)N*sizeof(int), stream);
    hipMemsetAsync(cursor, 0, (size_t)N*sizeof(int), stream);

    k_edge_basis<<<(E + 255)/256, 256, 0, stream>>>(edge_vec, rb, Yb, E);
    k_hist<<<(E + 255)/256, 256, 0, stream>>>(receivers, counts, E);
    k_scan<<<1, 1024, 0, stream>>>(counts, offsets, N);
    k_scatter<<<(E + 255)/256, 256, 0, stream>>>(receivers, offsets, cursor, elist, E);
    k_sort<<<(N + 255)/256, 256, 0, stream>>>(offsets, elist, N);
    k_embed<<<((size_t)N*64 + 255)/256, 256, 0, stream>>>(species, embed_w, h0a, N*64);

    float* hcur = h0a;
    float* hnxt = h0b;
    for (int l = 0; l < 2; ++l) {
        k_edge_mlp<<<(E + 63)/64, 64, 0, stream>>>(
            rb, hcur, senders,
            rad_w1 + (size_t)l*8*64,
            rad_w2 + (size_t)l*64*64,
            rad_w3 + (size_t)l*64*64,
            rad_w4 + (size_t)l*64*256,
            tbuf, E);
        k_node<<<((size_t)N*64 + 255)/256, 256, 0, stream>>>(
            tbuf, Yb, offsets, elist,
            mix_w + (size_t)l*4*64*64,
            read_w + (size_t)l*64,
            hnxt,
            (l == 0) ? nullptr : ener,
            (l == 0) ? ener : out,
            N);
        float* tmp = hcur; hcur = hnxt; hnxt = tmp;
    }
}